// Round 2
// baseline (114.260 us; speedup 1.0000x reference)
//
#include <hip/hip_runtime.h>
#include <math.h>

#define EPSC 1.1920928955078125e-07f
#define BATCH 8388608
#define IN_FEATS 2048
#define N_W_BLOCKS 16
#define ROWS_PER_CHUNK 64            // 1024 rows / 16 chunks
#define N_BCE_BLOCKS 1024
#define TOTAL_BLOCKS (N_W_BLOCKS + N_BCE_BLOCKS)

__device__ __forceinline__ float penalty_f(float x) {
    return 1.0f - __expf(-x * x) + fabsf(x);
}

__global__ __launch_bounds__(256) void fused_k(
        const float* __restrict__ p, const float* __restrict__ y,
        const float* __restrict__ W,
        float* __restrict__ colsq_part,   // [16][2048]
        float* __restrict__ bce_part,     // [1024]
        unsigned int* __restrict__ counter,
        float* __restrict__ out) {
    const int b = blockIdx.x;
    const int t = threadIdx.x;

    if (b < N_W_BLOCKS) {
        // ---- column sum-of-squares for a 64-row chunk of W ----
        const float4* base4 = (const float4*)(W + (size_t)b * ROWS_PER_CHUNK * IN_FEATS);
        float4 a0 = {0.f, 0.f, 0.f, 0.f};
        float4 a1 = {0.f, 0.f, 0.f, 0.f};
        #pragma unroll 8
        for (int r = 0; r < ROWS_PER_CHUNK; ++r) {
            float4 w0 = base4[r * 512 + t];        // cols 4t..4t+3
            float4 w1 = base4[r * 512 + t + 256];  // cols 1024+4t..
            a0.x = fmaf(w0.x, w0.x, a0.x);
            a0.y = fmaf(w0.y, w0.y, a0.y);
            a0.z = fmaf(w0.z, w0.z, a0.z);
            a0.w = fmaf(w0.w, w0.w, a0.w);
            a1.x = fmaf(w1.x, w1.x, a1.x);
            a1.y = fmaf(w1.y, w1.y, a1.y);
            a1.z = fmaf(w1.z, w1.z, a1.z);
            a1.w = fmaf(w1.w, w1.w, a1.w);
        }
        float4* cp4 = (float4*)(colsq_part + b * IN_FEATS);
        cp4[t] = a0;
        cp4[t + 256] = a1;
    } else {
        // ---- BCE partial over a slice of p,y ----
        const int bb = b - N_W_BLOCKS;
        const float4* p4 = (const float4*)p;
        const float4* y4 = (const float4*)y;
        const int tid = bb * 256 + t;
        const int stride = N_BCE_BLOCKS * 256;     // 262144
        float acc = 0.0f;
        #pragma unroll
        for (int it = 0; it < (BATCH / 4) / (N_BCE_BLOCKS * 256); ++it) {  // 8
            int i = tid + it * stride;
            float4 pv = p4[i];
            float4 yv = y4[i];
            float pp[4] = {pv.x, pv.y, pv.z, pv.w};
            float yy[4] = {yv.x, yv.y, yv.z, yv.w};
            #pragma unroll
            for (int k = 0; k < 4; ++k) {
                float pc  = fminf(fmaxf(pp[k],        EPSC), 1.0f - EPSC);
                float pmc = fminf(fmaxf(1.0f - pp[k], EPSC), 1.0f - EPSC);
                acc -= 0.7f * yy[k] * __logf(pc) + 0.3f * (1.0f - yy[k]) * __logf(pmc);
            }
        }
        __shared__ float s[256];
        s[t] = acc;
        __syncthreads();
        #pragma unroll
        for (int o = 128; o > 0; o >>= 1) {
            if (t < o) s[t] += s[t + o];
            __syncthreads();
        }
        if (t == 0) bce_part[bb] = s[0];
    }

    // ---- last-block-done: the final block to finish does the finalize ----
    __threadfence();                       // release: partials visible device-wide
    __shared__ unsigned int lastFlag;
    if (t == 0) {
        unsigned int prev = atomicAdd(counter, 1u);
        lastFlag = (prev == TOTAL_BLOCKS - 1) ? 1u : 0u;
    }
    __syncthreads();
    if (lastFlag == 0u) return;
    __threadfence();                       // acquire: see all partials

    // ---- finalize (one 256-thread block) ----
    __shared__ float cn[IN_FEATS];
    #pragma unroll
    for (int j = 0; j < IN_FEATS / 256; ++j) {     // 8 cols per thread
        int c = t + j * 256;
        float sum = 0.0f;
        #pragma unroll
        for (int k = 0; k < N_W_BLOCKS; ++k) sum += colsq_part[k * IN_FEATS + c];
        cn[c] = sqrtf(sum);
    }
    __syncthreads();

    float reg = 0.0f;
    #pragma unroll
    for (int j = 0; j < 4; ++j)                     // tail cols 1024..2047
        reg += penalty_f(cn[1024 + t + j * 256]);
    if (t < 64) {                                   // 64 groups of 16
        float gs = 0.0f;
        #pragma unroll
        for (int k = 0; k < 16; ++k) gs += cn[t * 16 + k];
        reg += penalty_f(gs * (1.0f / 16.0f));
    }
    float bce = 0.0f;
    #pragma unroll
    for (int j = 0; j < 4; ++j)
        bce += bce_part[t + j * 256];

    __shared__ float sr[256], sb[256];
    sr[t] = reg;
    sb[t] = bce;
    __syncthreads();
    #pragma unroll
    for (int o = 128; o > 0; o >>= 1) {
        if (t < o) { sr[t] += sr[t + o]; sb[t] += sb[t + o]; }
        __syncthreads();
    }
    if (t == 0) {
        out[0] = sb[0] * (1.0f / (float)BATCH) + 0.01f * sr[0];
    }
}

extern "C" void kernel_launch(void* const* d_in, const int* in_sizes, int n_in,
                              void* d_out, int out_size, void* d_ws, size_t ws_size,
                              hipStream_t stream) {
    const float* p = (const float*)d_in[0];
    const float* y = (const float*)d_in[1];
    const float* W = (const float*)d_in[2];
    float* out = (float*)d_out;

    float* colsq = (float*)d_ws;                          // 16*2048 floats
    float* bcep  = colsq + N_W_BLOCKS * IN_FEATS;         // 1024 floats
    unsigned int* counter = (unsigned int*)(bcep + N_BCE_BLOCKS);

    hipMemsetAsync(counter, 0, sizeof(unsigned int), stream);
    fused_k<<<TOTAL_BLOCKS, 256, 0, stream>>>(p, y, W, colsq, bcep, counter, out);
}

// Round 3
// 21.555 us; speedup vs baseline: 5.3009x; 5.3009x over previous
//
#include <hip/hip_runtime.h>
#include <math.h>

#define EPSC 1.1920928955078125e-07f
#define BATCH 8388608
#define IN_FEATS 2048
#define N_COL_BLOCKS 8               // 8 blocks x 256 threads cover 2048 columns
#define N_ROW_CHUNKS 16              // 16 chunks x 64 rows cover 1024 rows
#define ROWS_PER_CHUNK 64
#define N_W_BLOCKS (N_COL_BLOCKS * N_ROW_CHUNKS)   // 128
#define N_BCE_BLOCKS 1024
#define TOTAL_BLOCKS (N_W_BLOCKS + N_BCE_BLOCKS)   // 1152

__device__ __forceinline__ float penalty_f(float x) {
    return 1.0f - __expf(-x * x) + fabsf(x);
}

// Kernel A: all partials in one dispatch. Blocks 0..127: column sum-of-squares
// of W (64-KB tiles). Blocks 128..1151: BCE partial sums (64 KB of p+y each).
// Disjoint writes, no fences/atomics — the kernel boundary is the sync.
__global__ __launch_bounds__(256) void partials_k(
        const float* __restrict__ p, const float* __restrict__ y,
        const float* __restrict__ W,
        float* __restrict__ colsq_part,   // [16][2048]
        float* __restrict__ bce_part) {   // [1024]
    const int b = blockIdx.x;
    const int t = threadIdx.x;

    if (b < N_W_BLOCKS) {
        const int cb    = b & (N_COL_BLOCKS - 1);   // 0..7
        const int chunk = b >> 3;                   // 0..15
        const int col   = cb * 256 + t;
        const float* base = W + (size_t)chunk * ROWS_PER_CHUNK * IN_FEATS + col;
        float acc = 0.0f;
        #pragma unroll 8
        for (int r = 0; r < ROWS_PER_CHUNK; ++r) {
            float w = base[(size_t)r * IN_FEATS];
            acc = fmaf(w, w, acc);
        }
        colsq_part[chunk * IN_FEATS + col] = acc;
    } else {
        const int bb = b - N_W_BLOCKS;
        const float4* p4 = (const float4*)p;
        const float4* y4 = (const float4*)y;
        const int tid = bb * 256 + t;
        const int stride = N_BCE_BLOCKS * 256;      // 262144 float4 slots
        float acc = 0.0f;
        #pragma unroll
        for (int it = 0; it < (BATCH / 4) / stride; ++it) {   // 8
            int i = tid + it * stride;
            float4 pv = p4[i];
            float4 yv = y4[i];
            float pp[4] = {pv.x, pv.y, pv.z, pv.w};
            float yy[4] = {yv.x, yv.y, yv.z, yv.w};
            #pragma unroll
            for (int k = 0; k < 4; ++k) {
                // y is exactly 0.0 or 1.0: only one branch of the BCE survives.
                bool pos = yy[k] > 0.5f;
                float x  = pos ? pp[k] : 1.0f - pp[k];
                float w  = pos ? 0.7f : 0.3f;
                float xc = fminf(fmaxf(x, EPSC), 1.0f - EPSC);
                acc -= w * __logf(xc);
            }
        }
        __shared__ float s[256];
        s[t] = acc;
        __syncthreads();
        #pragma unroll
        for (int o = 128; o > 0; o >>= 1) {
            if (t < o) s[t] += s[t + o];
            __syncthreads();
        }
        if (t == 0) bce_part[bb] = s[0];
    }
}

// Kernel B: single 1024-thread block reads 128 KB of colsq partials + 4 KB of
// BCE partials and produces the scalar.
__global__ __launch_bounds__(1024) void finalize_k(
        const float* __restrict__ bce_part,
        const float* __restrict__ colsq_part,
        float* __restrict__ out) {
    __shared__ float cn[IN_FEATS];
    const int t = threadIdx.x;

    #pragma unroll
    for (int j = 0; j < IN_FEATS / 1024; ++j) {     // 2 cols per thread
        int c = t + j * 1024;
        float sum = 0.0f;
        #pragma unroll
        for (int k = 0; k < N_ROW_CHUNKS; ++k) sum += colsq_part[k * IN_FEATS + c];
        cn[c] = sqrtf(sum);
    }
    __syncthreads();

    float reg = penalty_f(cn[1024 + t]);            // tail cols, 1 per thread
    if (t < 64) {                                   // 64 groups of 16
        float gs = 0.0f;
        #pragma unroll
        for (int k = 0; k < 16; ++k) gs += cn[t * 16 + k];
        reg += penalty_f(gs * (1.0f / 16.0f));
    }
    float bce = bce_part[t];                        // exactly 1024 partials

    __shared__ float sr[1024], sb[1024];
    sr[t] = reg;
    sb[t] = bce;
    __syncthreads();
    #pragma unroll
    for (int o = 512; o > 0; o >>= 1) {
        if (t < o) { sr[t] += sr[t + o]; sb[t] += sb[t + o]; }
        __syncthreads();
    }
    if (t == 0) {
        out[0] = sb[0] * (1.0f / (float)BATCH) + 0.01f * sr[0];
    }
}

extern "C" void kernel_launch(void* const* d_in, const int* in_sizes, int n_in,
                              void* d_out, int out_size, void* d_ws, size_t ws_size,
                              hipStream_t stream) {
    const float* p = (const float*)d_in[0];
    const float* y = (const float*)d_in[1];
    const float* W = (const float*)d_in[2];
    float* out = (float*)d_out;

    float* colsq = (float*)d_ws;                          // 16*2048 floats
    float* bcep  = colsq + N_ROW_CHUNKS * IN_FEATS;       // 1024 floats

    partials_k<<<TOTAL_BLOCKS, 256, 0, stream>>>(p, y, W, colsq, bcep);
    finalize_k<<<1, 1024, 0, stream>>>(bcep, colsq, out);
}